// Round 6
// baseline (258.578 us; speedup 1.0000x reference)
//
#include <hip/hip_runtime.h>

// MMD loss, N=4096 per side, D=256, fp32.
// R22: ABLATION ROUND. Five structural rewrites (R18 occupancy, R19 fp8,
//      R20 LDS-DMA, R21 no-atomic) each predicted >=2x, delivered <=10%.
//      Per skill rule (common-mistake #8): stop guessing, ablate.
//      Budget: fill 42 (harness, untouchable) + conv ~5 + scale ~4 +
//      pairs ~33 + fin ~2 + gaps ~15. k_pairs floor ~14-16 us (MFMA 8.3
//      triangular-fp8 + epi VALU ~12 busy + stage ~4, overlapped); ~17 us
//      of stall is unlocated. Production path BYTE-FROZEN from R21; three
//      k_abl<V,REPS> dispatches appended AFTER k_fin, writing scratch,
//      internally repeated to exceed the 42 us fills -> visible in top-5:
//        k_abl<7,3>: full body x3        (stage+MFMA+epilogue)
//        k_abl<1,6>: staging-only x6     (DMA+vmcnt0+barrier)
//        k_abl<6,4>: no-stage x4         (ds_read junk+MFMA+epilogue)
//      Pre-committed: additive -> convoy (anti-phase next); abl3~abl1 ->
//      epilogue binder (packed f32 + multi-acc; tsum is a 320-long strict-
//      order dependent add chain); abl2~abl1 -> staging binder. Absent
//      from top-5 => <11 us/pass (also informative).
//      Lessons: NO __threadfence (R8-R10), NO cooperative (R17), unrolled
//      indices only (R8/R9), occupancy/bytes/atomics not the lever (R18-21).

#define NROWS 8192
#define HALF  4096
#define DIM   256
#define CONVB 256
#define NTILE 2080        // 128x128 tiles: 64*65/2, J>=I

typedef float f32x4 __attribute__((ext_vector_type(4)));

__device__ __forceinline__ const float* row_ptr(const float* src, const float* tgt, int r) {
    return (r < HALF) ? (src + (size_t)r * DIM) : (tgt + (size_t)(r - HALF) * DIM);
}

__device__ __forceinline__ void gload_lds16(const void* g, void* l) {
    __builtin_amdgcn_global_load_lds(
        (const __attribute__((address_space(1))) unsigned int*)g,
        (__attribute__((address_space(3))) unsigned int*)l, 16, 0, 0);
}

// --- Phase 0: fp32 -> fp8 plane (tiled, k-interleaved) + sq/colsum/S1 ---
__global__ __launch_bounds__(256) void k_conv(const float* __restrict__ src,
                                              const float* __restrict__ tgt,
                                              unsigned char* __restrict__ hi,
                                              float* __restrict__ sq,
                                              float* __restrict__ part,
                                              double* __restrict__ parts1,
                                              float* __restrict__ out) {
    __shared__ __align__(16) unsigned char sh8[32 * 256];  // 8 KB, octet-swizzled
    __shared__ float4 cs[4][64];
    __shared__ double s1s[4];

    int w = threadIdx.x >> 6, lane = threadIdx.x & 63;
    int r0 = blockIdx.x * 32;

    float4 v[8];
    #pragma unroll
    for (int i = 0; i < 8; ++i) {
        int row = r0 + w * 8 + i;
        v[i] = ((const float4*)row_ptr(src, tgt, row))[lane];
    }

    float4 csum = {0.f, 0.f, 0.f, 0.f};
    double s1w = 0.0;
    #pragma unroll
    for (int i = 0; i < 8; ++i) {
        int rl  = w * 8 + i;
        float xs[4] = {v[i].x, v[i].y, v[i].z, v[i].w};
        int pk = __builtin_amdgcn_cvt_pk_fp8_f32(xs[0], xs[1], 0, false);
        pk     = __builtin_amdgcn_cvt_pk_fp8_f32(xs[2], xs[3], pk, true);
        int o  = lane >> 1, h = lane & 1;
        *(int*)&sh8[rl * 256 + (((o ^ rl) & 31) << 3) + (h << 2)] = pk;
        csum.x += xs[0]; csum.y += xs[1]; csum.z += xs[2]; csum.w += xs[3];
        float sf = xs[0]*xs[0] + xs[1]*xs[1] + xs[2]*xs[2] + xs[3]*xs[3];
        float q0 = __builtin_amdgcn_cvt_f32_fp8(pk, 0);
        float q1 = __builtin_amdgcn_cvt_f32_fp8(pk, 1);
        float q2 = __builtin_amdgcn_cvt_f32_fp8(pk, 2);
        float q3 = __builtin_amdgcn_cvt_f32_fp8(pk, 3);
        float sQ = q0*q0 + q1*q1 + q2*q2 + q3*q3;
        #pragma unroll
        for (int off = 32; off; off >>= 1) {
            sf += __shfl_xor(sf, off, 64);
            sQ += __shfl_xor(sQ, off, 64);
        }
        if (lane == 0) { sq[r0 + rl] = sQ; s1w += (double)sf; }
    }
    __syncthreads();
    int panel = blockIdx.x >> 2, quarter = blockIdx.x & 3;
    #pragma unroll
    for (int c = threadIdx.x; c < 512; c += 256) {
        int u = c >> 5, rl = c & 31;
        int tt = u >> 2, j = u & 3;
        int o0 = 8 * tt + j;
        int o1 = 8 * tt + 4 + j;
        unsigned long long q0 = *(const unsigned long long*)
            &sh8[rl * 256 + (((o0 ^ rl) & 31) << 3)];
        unsigned long long q1 = *(const unsigned long long*)
            &sh8[rl * 256 + (((o1 ^ rl) & 31) << 3)];
        ulonglong2 q = {q0, q1};
        size_t goff = ((size_t)panel * 2048 + (size_t)u * 128 + quarter * 32 + rl);
        ((ulonglong2*)hi)[goff] = q;
    }
    cs[w][lane] = csum;
    if (lane == 0) s1s[w] = s1w;
    __syncthreads();
    if (w == 0) {
        float4 a = cs[0][lane], b = cs[1][lane], c = cs[2][lane], d = cs[3][lane];
        float4 tot = {a.x + b.x + c.x + d.x, a.y + b.y + c.y + d.y,
                      a.z + b.z + c.z + d.z, a.w + b.w + c.w + d.w};
        *(float4*)&part[(size_t)blockIdx.x * DIM + lane * 4] = tot;
        if (lane == 0) parts1[blockIdx.x] = s1s[0] + s1s[1] + s1s[2] + s1s[3];
    }
    if (blockIdx.x == 0 && threadIdx.x == 0) out[0] = 0.0f;
}

// --- Phase 1: bandwidth -> exp2 scale factor ---
__global__ __launch_bounds__(256) void k_scale(const double* __restrict__ parts1,
                                               const float* __restrict__ part,
                                               float* __restrict__ scale) {
    __shared__ double sh[256];
    int t = threadIdx.x;
    sh[t] = parts1[t];
    __syncthreads();
    for (int off = 128; off; off >>= 1) {
        if (t < off) sh[t] += sh[t + off];
        __syncthreads();
    }
    double S1 = sh[0];
    __syncthreads();
    float c0 = 0.f, c1 = 0.f, c2 = 0.f, c3 = 0.f;
    #pragma unroll 16
    for (int b = 0; b < CONVB; b += 4) {
        c0 += part[(b + 0) * DIM + t];
        c1 += part[(b + 1) * DIM + t];
        c2 += part[(b + 2) * DIM + t];
        c3 += part[(b + 3) * DIM + t];
    }
    double c = (double)((c0 + c1) + (c2 + c3));
    sh[t] = c * c;
    __syncthreads();
    for (int off = 128; off; off >>= 1) {
        if (t < off) sh[t] += sh[t + off];
        __syncthreads();
    }
    if (t == 0) {
        double S2    = sh[0];
        double n     = (double)NROWS;
        double sumL2 = 2.0 * n * S1 - 2.0 * S2;
        double bw    = sumL2 / (n * n - n) / 4.0;
        *scale = (float)(-1.0 / (16.0 * bw * 0.69314718055994530942));
    }
}

// --- Phase 2: LDS-staged fp8 MFMA pair kernel (PRODUCTION, frozen R21) ---
__global__ __launch_bounds__(256, 2) void k_pairs(const unsigned char* __restrict__ hi,
                                                  const float* __restrict__ sq,
                                                  const float* __restrict__ scale_p,
                                                  float* __restrict__ pb) {
    __shared__ __align__(16) ulonglong2 ldsA[2048];
    __shared__ __align__(16) ulonglong2 ldsB[2048];
    __shared__ float wsum[4];

    int id = blockIdx.x;
    int I = 0;
    for (;;) {
        int cnt = 64 - I;
        if (id < cnt) break;
        id -= cnt; ++I;
    }
    int J = I + id;

    int t    = threadIdx.x;
    int lane = t & 63;
    int w    = t >> 6;
    int lr   = lane & 15, lq = lane >> 4;
    int wr   = w >> 1, wc = w & 1;

    float wgt = (J == I) ? 1.0f : 2.0f;
    float sgn = ((I < 32) == (J < 32)) ? 1.0f : -1.0f;

    const ulonglong2* plane = (const ulonglong2*)hi;
    int nIns = (J == I) ? 32 : 64;
    for (int i = 0; i < 16; ++i) {
        int k = w + 4 * i;
        if (k >= nIns) break;
        int p  = k >> 5;
        int u  = (k >> 1) & 15;
        int h  = k & 1;
        int rg = (h * 64 + lane) ^ ((u & 3) << 1);
        size_t gUnit = (size_t)(p ? J : I) * 2048 + (size_t)u * 128 + rg;
        ulonglong2* ldst = (p ? ldsB : ldsA) + (u * 128 + h * 64);
        gload_lds16(plane + gUnit, ldst);
    }
    asm volatile("s_waitcnt vmcnt(0)");
    __syncthreads();

    const ulonglong2* lA = ldsA;
    const ulonglong2* lB = (J == I) ? ldsA : ldsB;
    int lrx = lr ^ (lq << 1);
    const ulonglong2* pAl = lA + lq * 128 + wr * 64 + lrx;
    const ulonglong2* pBl = lB + lq * 128 + wc * 64 + lrx;

    f32x4 acc[4][4];
    #pragma unroll
    for (int m = 0; m < 4; ++m)
        #pragma unroll
        for (int n = 0; n < 4; ++n) acc[m][n] = (f32x4){0.f, 0.f, 0.f, 0.f};

    #pragma unroll
    for (int tt = 0; tt < 4; ++tt) {
        ulonglong2 fA[4], fB[4];
        #pragma unroll
        for (int m = 0; m < 4; ++m) fA[m] = pAl[tt * 512 + m * 16];
        #pragma unroll
        for (int n = 0; n < 4; ++n) fB[n] = pBl[tt * 512 + n * 16];
        #pragma unroll
        for (int m = 0; m < 4; ++m)
            #pragma unroll
            for (int n = 0; n < 4; ++n)
                acc[m][n] = __builtin_amdgcn_mfma_f32_16x16x32_fp8_fp8(
                    (long)fA[m].x, (long)fB[n].x, acc[m][n], 0, 0, 0);
        #pragma unroll
        for (int m = 0; m < 4; ++m)
            #pragma unroll
            for (int n = 0; n < 4; ++n)
                acc[m][n] = __builtin_amdgcn_mfma_f32_16x16x32_fp8_fp8(
                    (long)fA[m].y, (long)fB[n].y, acc[m][n], 0, 0, 0);
    }

    float scale = *scale_p;
    int ro_eff = I * 128 + wr * 64;
    int co_eff = J * 128 + wc * 64;
    float4 sqa4[4];
    float  sqbv[4];
    #pragma unroll
    for (int m = 0; m < 4; ++m) sqa4[m] = *(const float4*)&sq[ro_eff + m * 16 + lq * 4];
    #pragma unroll
    for (int n = 0; n < 4; ++n) sqbv[n] = sq[co_eff + n * 16 + lr];

    float tsum = 0.0f;
    #pragma unroll
    for (int m = 0; m < 4; ++m) {
        float sa[4] = {sqa4[m].x, sqa4[m].y, sqa4[m].z, sqa4[m].w};
        #pragma unroll
        for (int n = 0; n < 4; ++n) {
            #pragma unroll
            for (int r = 0; r < 4; ++r) {
                float L2  = sa[r] + sqbv[n] - 2.0f * acc[m][n][r];
                float u   = __builtin_amdgcn_exp2f(scale * L2);
                float u2  = u * u;
                float u4  = u2 * u2;
                float u8  = u4 * u4;
                float u16 = u8 * u8;
                tsum += u + u2 + u4 + u8 + u16;
            }
        }
    }

    #pragma unroll
    for (int off = 32; off; off >>= 1) tsum += __shfl_xor(tsum, off, 64);
    if (lane == 0) wsum[w] = tsum;
    __syncthreads();
    if (t == 0) {
        float tot = wsum[0] + wsum[1] + wsum[2] + wsum[3];
        pb[blockIdx.x] = tot * sgn * wgt * (1.0f / ((float)HALF * (float)HALF));
    }
}

// --- Phase 3: reduce per-block partials -> out ---
__global__ __launch_bounds__(256) void k_fin(const float* __restrict__ pb,
                                             float* __restrict__ out) {
    __shared__ float sh[4];
    int t = threadIdx.x, lane = t & 63, w = t >> 6;
    float s = 0.f;
    for (int i = t; i < NTILE; i += 256) s += pb[i];
    #pragma unroll
    for (int off = 32; off; off >>= 1) s += __shfl_xor(s, off, 64);
    if (lane == 0) sh[w] = s;
    __syncthreads();
    if (t == 0) out[0] = sh[0] + sh[1] + sh[2] + sh[3];
}

// ===== R22 ablation kernels: V bit0=stage, bit1=mfma, bit2=epilogue =====
// Writes scratch only; appended after k_fin; REPS-scaled for top-5 visibility.
template<int V, int REPS>
__global__ __launch_bounds__(256, 2) void k_abl(const unsigned char* __restrict__ hi,
                                                const float* __restrict__ sq,
                                                const float* __restrict__ scale_p,
                                                float* __restrict__ pbx) {
    constexpr bool DO_S = (V & 1), DO_M = (V & 2), DO_E = (V & 4);
    __shared__ __align__(16) ulonglong2 ldsA[2048];
    __shared__ __align__(16) ulonglong2 ldsB[2048];
    __shared__ float wsum[4];

    int id = blockIdx.x;
    int I = 0;
    for (;;) {
        int cnt = 64 - I;
        if (id < cnt) break;
        id -= cnt; ++I;
    }
    int J = I + id;

    int t    = threadIdx.x;
    int lane = t & 63;
    int w    = t >> 6;
    int lr   = lane & 15, lq = lane >> 4;
    int wr   = w >> 1, wc = w & 1;

    const ulonglong2* plane = (const ulonglong2*)hi;
    int nIns = (J == I) ? 32 : 64;
    int lrx = lr ^ (lq << 1);
    const ulonglong2* lA = ldsA;
    const ulonglong2* lB = (J == I) ? ldsA : ldsB;
    const ulonglong2* pAl = lA + lq * 128 + wr * 64 + lrx;
    const ulonglong2* pBl = lB + lq * 128 + wc * 64 + lrx;
    float scale = *scale_p;

    float keep = 0.f;
    #pragma unroll 1
    for (int rep = 0; rep < REPS; ++rep) {
        if (DO_S) {
            for (int i = 0; i < 16; ++i) {
                int k = w + 4 * i;
                if (k >= nIns) break;
                int p  = k >> 5;
                int u  = (k >> 1) & 15;
                int h  = k & 1;
                int rg = (h * 64 + lane) ^ ((u & 3) << 1);
                size_t gUnit = (size_t)(p ? J : I) * 2048 + (size_t)u * 128 + rg;
                ulonglong2* ldst = (p ? ldsB : ldsA) + (u * 128 + h * 64);
                gload_lds16(plane + gUnit, ldst);
            }
            asm volatile("s_waitcnt vmcnt(0)");
        }
        __syncthreads();

        float tsum = 0.0f;
        if (DO_M) {
            f32x4 acc[4][4];
            #pragma unroll
            for (int m = 0; m < 4; ++m)
                #pragma unroll
                for (int n = 0; n < 4; ++n) acc[m][n] = (f32x4){0.f, 0.f, 0.f, 0.f};
            #pragma unroll
            for (int tt = 0; tt < 4; ++tt) {
                ulonglong2 fA[4], fB[4];
                #pragma unroll
                for (int m = 0; m < 4; ++m) fA[m] = pAl[tt * 512 + m * 16];
                #pragma unroll
                for (int n = 0; n < 4; ++n) fB[n] = pBl[tt * 512 + n * 16];
                #pragma unroll
                for (int m = 0; m < 4; ++m)
                    #pragma unroll
                    for (int n = 0; n < 4; ++n)
                        acc[m][n] = __builtin_amdgcn_mfma_f32_16x16x32_fp8_fp8(
                            (long)fA[m].x, (long)fB[n].x, acc[m][n], 0, 0, 0);
                #pragma unroll
                for (int m = 0; m < 4; ++m)
                    #pragma unroll
                    for (int n = 0; n < 4; ++n)
                        acc[m][n] = __builtin_amdgcn_mfma_f32_16x16x32_fp8_fp8(
                            (long)fA[m].y, (long)fB[n].y, acc[m][n], 0, 0, 0);
            }
            if (DO_E) {
                int ro_eff = I * 128 + wr * 64;
                int co_eff = J * 128 + wc * 64;
                float4 sqa4[4];
                float  sqbv[4];
                #pragma unroll
                for (int m = 0; m < 4; ++m) sqa4[m] = *(const float4*)&sq[ro_eff + m * 16 + lq * 4];
                #pragma unroll
                for (int n = 0; n < 4; ++n) sqbv[n] = sq[co_eff + n * 16 + lr];
                #pragma unroll
                for (int m = 0; m < 4; ++m) {
                    float sa[4] = {sqa4[m].x, sqa4[m].y, sqa4[m].z, sqa4[m].w};
                    #pragma unroll
                    for (int n = 0; n < 4; ++n) {
                        #pragma unroll
                        for (int r = 0; r < 4; ++r) {
                            float L2  = sa[r] + sqbv[n] - 2.0f * acc[m][n][r];
                            float u   = __builtin_amdgcn_exp2f(scale * L2);
                            float u2  = u * u;
                            float u4  = u2 * u2;
                            float u8  = u4 * u4;
                            float u16 = u8 * u8;
                            tsum += u + u2 + u4 + u8 + u16;
                        }
                    }
                }
            } else {
                // consume acc without epilogue (keepalive)
                #pragma unroll
                for (int m = 0; m < 4; ++m)
                    #pragma unroll
                    for (int n = 0; n < 4; ++n)
                        tsum += acc[m][n][0] + acc[m][n][3];
            }
        } else {
            // staging-only: consume LDS so nothing is removable
            tsum = ((const float*)ldsA)[t] + ((const float*)ldsB)[t];
        }
        keep += tsum;
        __syncthreads();
    }

    #pragma unroll
    for (int off = 32; off; off >>= 1) keep += __shfl_xor(keep, off, 64);
    if (lane == 0) wsum[w] = keep;
    __syncthreads();
    if (t == 0) pbx[blockIdx.x] = wsum[0] + wsum[1] + wsum[2] + wsum[3];
}

extern "C" void kernel_launch(void* const* d_in, const int* in_sizes, int n_in,
                              void* d_out, int out_size, void* d_ws, size_t ws_size,
                              hipStream_t stream) {
    const float* src = (const float*)d_in[0];
    const float* tgt = (const float*)d_in[1];
    float* out = (float*)d_out;

    char* ws = (char*)d_ws;
    float*  scale  = (float*)(ws + 16);                          // 4 B
    float*  sq     = (float*)(ws + 64);                          // 32768 B
    float*  part   = (float*)(ws + 64 + 32768);                  // 256*256*4 B
    double* parts1 = (double*)(ws + 64 + 32768 + 262144);        // 256*8 B
    unsigned char* hi = (unsigned char*)(ws + 297024);           // 2 MB, 16B-aligned
    float*  pb     = (float*)(ws + 2394176);                     // 2080*4 B
    float*  pbx    = (float*)(ws + 2402368);                     // scratch (ablation)

    k_conv <<<CONVB, 256, 0, stream>>>(src, tgt, hi, sq, part, parts1, out);
    k_scale<<<1, 256, 0, stream>>>(parts1, part, scale);
    k_pairs<<<NTILE, 256, 0, stream>>>(hi, sq, scale, pb);
    k_fin  <<<1, 256, 0, stream>>>(pb, out);

    // --- R22 ablation probes (scratch-only, after result is finalized) ---
    k_abl<7, 3><<<NTILE, 256, 0, stream>>>(hi, sq, scale, pbx);  // full x3
    k_abl<1, 6><<<NTILE, 256, 0, stream>>>(hi, sq, scale, pbx);  // stage-only x6
    k_abl<6, 4><<<NTILE, 256, 0, stream>>>(hi, sq, scale, pbx);  // no-stage x4
}

// Round 8
// 97.468 us; speedup vs baseline: 2.6530x; 2.6530x over previous
//
#include <hip/hip_runtime.h>

// MMD loss, N=4096 per side, D=256, fp32.
// R24 == R23 resubmitted byte-identical (R23's bench died on a container
//      infra failure, "MI355X container failed twice" -- no measurement).
// R23: packed-fp32 epilogue. R22 ablation located the binder: VALU-busy is
//      13.2-13.5 us INVARIANT across totally different data paths (R16
//      bf16/global vs R22 fp8/LDS-DMA) -> it's the shared EPILOGUE
//      (~34M outputs x {L2, exp2, 4 powers, 5 adds} ~= 12 VALU + 1 trans),
//      issuing 2x longer than MFMA (48.9% vs 24.9% back-to-back). Staging
//      and MFMA mostly hide under it; that's why R18-R21 data-path rewrites
//      moved <=10%.
//      Fix: epilogue on float2 ext-vectors -> v_pk_fma/add/mul_f32 (gfx950
//      full-rate packed fp32). r-pairs (0,1)/(2,3) processed together;
//      scale folded into precomputed s*sa / s*sqb so L2+scale is one
//      pk_fma; 5-term kernel sum as a tree; two independent packed
//      accumulators break the 320-add dependent chain. ~12 -> ~5.5 VALU
//      per output. IEEE fp32 math unchanged, only sum order (R13-verified
//      jitter tolerance). Everything else BYTE-FROZEN from R21.
//      Lessons: NO __threadfence (R8-R10), NO cooperative (R17), unrolled
//      indices only (R8/R9), occupancy/bytes/atomics not the lever
//      (R18-R21), binder = epilogue VALU (R22 ablation).

#define NROWS 8192
#define HALF  4096
#define DIM   256
#define CONVB 256
#define NTILE 2080        // 128x128 tiles: 64*65/2, J>=I

typedef float f32x4 __attribute__((ext_vector_type(4)));
typedef float f32x2 __attribute__((ext_vector_type(2)));

__device__ __forceinline__ const float* row_ptr(const float* src, const float* tgt, int r) {
    return (r < HALF) ? (src + (size_t)r * DIM) : (tgt + (size_t)(r - HALF) * DIM);
}

__device__ __forceinline__ void gload_lds16(const void* g, void* l) {
    __builtin_amdgcn_global_load_lds(
        (const __attribute__((address_space(1))) unsigned int*)g,
        (__attribute__((address_space(3))) unsigned int*)l, 16, 0, 0);
}

// --- Phase 0: fp32 -> fp8 plane (tiled, k-interleaved) + sq/colsum/S1 ---
__global__ __launch_bounds__(256) void k_conv(const float* __restrict__ src,
                                              const float* __restrict__ tgt,
                                              unsigned char* __restrict__ hi,
                                              float* __restrict__ sq,
                                              float* __restrict__ part,
                                              double* __restrict__ parts1,
                                              float* __restrict__ out) {
    __shared__ __align__(16) unsigned char sh8[32 * 256];  // 8 KB, octet-swizzled
    __shared__ float4 cs[4][64];
    __shared__ double s1s[4];

    int w = threadIdx.x >> 6, lane = threadIdx.x & 63;
    int r0 = blockIdx.x * 32;

    float4 v[8];
    #pragma unroll
    for (int i = 0; i < 8; ++i) {
        int row = r0 + w * 8 + i;
        v[i] = ((const float4*)row_ptr(src, tgt, row))[lane];
    }

    float4 csum = {0.f, 0.f, 0.f, 0.f};
    double s1w = 0.0;
    #pragma unroll
    for (int i = 0; i < 8; ++i) {
        int rl  = w * 8 + i;
        float xs[4] = {v[i].x, v[i].y, v[i].z, v[i].w};
        int pk = __builtin_amdgcn_cvt_pk_fp8_f32(xs[0], xs[1], 0, false);
        pk     = __builtin_amdgcn_cvt_pk_fp8_f32(xs[2], xs[3], pk, true);
        int o  = lane >> 1, h = lane & 1;
        *(int*)&sh8[rl * 256 + (((o ^ rl) & 31) << 3) + (h << 2)] = pk;
        csum.x += xs[0]; csum.y += xs[1]; csum.z += xs[2]; csum.w += xs[3];
        float sf = xs[0]*xs[0] + xs[1]*xs[1] + xs[2]*xs[2] + xs[3]*xs[3];
        float q0 = __builtin_amdgcn_cvt_f32_fp8(pk, 0);
        float q1 = __builtin_amdgcn_cvt_f32_fp8(pk, 1);
        float q2 = __builtin_amdgcn_cvt_f32_fp8(pk, 2);
        float q3 = __builtin_amdgcn_cvt_f32_fp8(pk, 3);
        float sQ = q0*q0 + q1*q1 + q2*q2 + q3*q3;
        #pragma unroll
        for (int off = 32; off; off >>= 1) {
            sf += __shfl_xor(sf, off, 64);
            sQ += __shfl_xor(sQ, off, 64);
        }
        if (lane == 0) { sq[r0 + rl] = sQ; s1w += (double)sf; }
    }
    __syncthreads();
    int panel = blockIdx.x >> 2, quarter = blockIdx.x & 3;
    #pragma unroll
    for (int c = threadIdx.x; c < 512; c += 256) {
        int u = c >> 5, rl = c & 31;
        int tt = u >> 2, j = u & 3;
        int o0 = 8 * tt + j;
        int o1 = 8 * tt + 4 + j;
        unsigned long long q0 = *(const unsigned long long*)
            &sh8[rl * 256 + (((o0 ^ rl) & 31) << 3)];
        unsigned long long q1 = *(const unsigned long long*)
            &sh8[rl * 256 + (((o1 ^ rl) & 31) << 3)];
        ulonglong2 q = {q0, q1};
        size_t goff = ((size_t)panel * 2048 + (size_t)u * 128 + quarter * 32 + rl);
        ((ulonglong2*)hi)[goff] = q;
    }
    cs[w][lane] = csum;
    if (lane == 0) s1s[w] = s1w;
    __syncthreads();
    if (w == 0) {
        float4 a = cs[0][lane], b = cs[1][lane], c = cs[2][lane], d = cs[3][lane];
        float4 tot = {a.x + b.x + c.x + d.x, a.y + b.y + c.y + d.y,
                      a.z + b.z + c.z + d.z, a.w + b.w + c.w + d.w};
        *(float4*)&part[(size_t)blockIdx.x * DIM + lane * 4] = tot;
        if (lane == 0) parts1[blockIdx.x] = s1s[0] + s1s[1] + s1s[2] + s1s[3];
    }
    if (blockIdx.x == 0 && threadIdx.x == 0) out[0] = 0.0f;
}

// --- Phase 1: bandwidth -> exp2 scale factor ---
__global__ __launch_bounds__(256) void k_scale(const double* __restrict__ parts1,
                                               const float* __restrict__ part,
                                               float* __restrict__ scale) {
    __shared__ double sh[256];
    int t = threadIdx.x;
    sh[t] = parts1[t];
    __syncthreads();
    for (int off = 128; off; off >>= 1) {
        if (t < off) sh[t] += sh[t + off];
        __syncthreads();
    }
    double S1 = sh[0];
    __syncthreads();
    float c0 = 0.f, c1 = 0.f, c2 = 0.f, c3 = 0.f;
    #pragma unroll 16
    for (int b = 0; b < CONVB; b += 4) {
        c0 += part[(b + 0) * DIM + t];
        c1 += part[(b + 1) * DIM + t];
        c2 += part[(b + 2) * DIM + t];
        c3 += part[(b + 3) * DIM + t];
    }
    double c = (double)((c0 + c1) + (c2 + c3));
    sh[t] = c * c;
    __syncthreads();
    for (int off = 128; off; off >>= 1) {
        if (t < off) sh[t] += sh[t + off];
        __syncthreads();
    }
    if (t == 0) {
        double S2    = sh[0];
        double n     = (double)NROWS;
        double sumL2 = 2.0 * n * S1 - 2.0 * S2;
        double bw    = sumL2 / (n * n - n) / 4.0;
        *scale = (float)(-1.0 / (16.0 * bw * 0.69314718055994530942));
    }
}

// --- Phase 2: LDS-staged fp8 MFMA pair kernel; PACKED-f32 epilogue ---
__global__ __launch_bounds__(256, 2) void k_pairs(const unsigned char* __restrict__ hi,
                                                  const float* __restrict__ sq,
                                                  const float* __restrict__ scale_p,
                                                  float* __restrict__ pb) {
    __shared__ __align__(16) ulonglong2 ldsA[2048];
    __shared__ __align__(16) ulonglong2 ldsB[2048];
    __shared__ float wsum[4];

    int id = blockIdx.x;
    int I = 0;
    for (;;) {
        int cnt = 64 - I;
        if (id < cnt) break;
        id -= cnt; ++I;
    }
    int J = I + id;

    int t    = threadIdx.x;
    int lane = t & 63;
    int w    = t >> 6;
    int lr   = lane & 15, lq = lane >> 4;
    int wr   = w >> 1, wc = w & 1;

    float wgt = (J == I) ? 1.0f : 2.0f;
    float sgn = ((I < 32) == (J < 32)) ? 1.0f : -1.0f;

    const ulonglong2* plane = (const ulonglong2*)hi;
    int nIns = (J == I) ? 32 : 64;
    for (int i = 0; i < 16; ++i) {
        int k = w + 4 * i;
        if (k >= nIns) break;
        int p  = k >> 5;
        int u  = (k >> 1) & 15;
        int h  = k & 1;
        int rg = (h * 64 + lane) ^ ((u & 3) << 1);
        size_t gUnit = (size_t)(p ? J : I) * 2048 + (size_t)u * 128 + rg;
        ulonglong2* ldst = (p ? ldsB : ldsA) + (u * 128 + h * 64);
        gload_lds16(plane + gUnit, ldst);
    }
    asm volatile("s_waitcnt vmcnt(0)");
    __syncthreads();

    const ulonglong2* lA = ldsA;
    const ulonglong2* lB = (J == I) ? ldsA : ldsB;
    int lrx = lr ^ (lq << 1);
    const ulonglong2* pAl = lA + lq * 128 + wr * 64 + lrx;
    const ulonglong2* pBl = lB + lq * 128 + wc * 64 + lrx;

    f32x4 acc[4][4];
    #pragma unroll
    for (int m = 0; m < 4; ++m)
        #pragma unroll
        for (int n = 0; n < 4; ++n) acc[m][n] = (f32x4){0.f, 0.f, 0.f, 0.f};

    #pragma unroll
    for (int tt = 0; tt < 4; ++tt) {
        ulonglong2 fA[4], fB[4];
        #pragma unroll
        for (int m = 0; m < 4; ++m) fA[m] = pAl[tt * 512 + m * 16];
        #pragma unroll
        for (int n = 0; n < 4; ++n) fB[n] = pBl[tt * 512 + n * 16];
        #pragma unroll
        for (int m = 0; m < 4; ++m)
            #pragma unroll
            for (int n = 0; n < 4; ++n)
                acc[m][n] = __builtin_amdgcn_mfma_f32_16x16x32_fp8_fp8(
                    (long)fA[m].x, (long)fB[n].x, acc[m][n], 0, 0, 0);
        #pragma unroll
        for (int m = 0; m < 4; ++m)
            #pragma unroll
            for (int n = 0; n < 4; ++n)
                acc[m][n] = __builtin_amdgcn_mfma_f32_16x16x32_fp8_fp8(
                    (long)fA[m].y, (long)fB[n].y, acc[m][n], 0, 0, 0);
    }

    // ---- R23 epilogue: packed-f32 (v_pk_*), r-pairs, scale pre-folded ----
    // u = exp2(s*L2), L2 = sa + sqb - 2*acc  =>  arg = (s*sa + s*sqb) - 2s*acc
    float s = *scale_p;
    int ro_eff = I * 128 + wr * 64;
    int co_eff = J * 128 + wc * 64;
    float4 sqa4[4];
    float  sqbv[4];
    #pragma unroll
    for (int m = 0; m < 4; ++m) sqa4[m] = *(const float4*)&sq[ro_eff + m * 16 + lq * 4];
    #pragma unroll
    for (int n = 0; n < 4; ++n) sqbv[n] = s * sq[co_eff + n * 16 + lr];

    f32x2 ssa01[4], ssa23[4];
    #pragma unroll
    for (int m = 0; m < 4; ++m) {
        ssa01[m] = (f32x2){s * sqa4[m].x, s * sqa4[m].y};
        ssa23[m] = (f32x2){s * sqa4[m].z, s * sqa4[m].w};
    }
    f32x2 m2s = {-2.0f * s, -2.0f * s};

    f32x2 t0 = {0.f, 0.f}, t1 = {0.f, 0.f};    // independent packed accumulators
    #pragma unroll
    for (int m = 0; m < 4; ++m) {
        #pragma unroll
        for (int n = 0; n < 4; ++n) {
            f32x2 sbn = {sqbv[n], sqbv[n]};
            f32x2 a01 = {acc[m][n][0], acc[m][n][1]};
            f32x2 a23 = {acc[m][n][2], acc[m][n][3]};
            f32x2 e01 = (ssa01[m] + sbn) + m2s * a01;   // pk_add + pk_fma
            f32x2 e23 = (ssa23[m] + sbn) + m2s * a23;
            f32x2 u01, u23;
            u01.x = __builtin_amdgcn_exp2f(e01.x);
            u01.y = __builtin_amdgcn_exp2f(e01.y);
            u23.x = __builtin_amdgcn_exp2f(e23.x);
            u23.y = __builtin_amdgcn_exp2f(e23.y);
            f32x2 p2a = u01 * u01, p4a = p2a * p2a, p8a = p4a * p4a, p16a = p8a * p8a;
            f32x2 p2b = u23 * u23, p4b = p2b * p2b, p8b = p4b * p4b, p16b = p8b * p8b;
            t0 += ((u01 + p2a) + (p4a + p8a)) + p16a;   // 5 kernel scales, tree
            t1 += ((u23 + p2b) + (p4b + p8b)) + p16b;
        }
    }
    float tsum = (t0.x + t0.y) + (t1.x + t1.y);

    #pragma unroll
    for (int off = 32; off; off >>= 1) tsum += __shfl_xor(tsum, off, 64);
    if (lane == 0) wsum[w] = tsum;
    __syncthreads();
    if (t == 0) {
        float tot = wsum[0] + wsum[1] + wsum[2] + wsum[3];
        pb[blockIdx.x] = tot * sgn * wgt * (1.0f / ((float)HALF * (float)HALF));
    }
}

// --- Phase 3: reduce per-block partials -> out ---
__global__ __launch_bounds__(256) void k_fin(const float* __restrict__ pb,
                                             float* __restrict__ out) {
    __shared__ float sh[4];
    int t = threadIdx.x, lane = t & 63, w = t >> 6;
    float s = 0.f;
    for (int i = t; i < NTILE; i += 256) s += pb[i];
    #pragma unroll
    for (int off = 32; off; off >>= 1) s += __shfl_xor(s, off, 64);
    if (lane == 0) sh[w] = s;
    __syncthreads();
    if (t == 0) out[0] = sh[0] + sh[1] + sh[2] + sh[3];
}

extern "C" void kernel_launch(void* const* d_in, const int* in_sizes, int n_in,
                              void* d_out, int out_size, void* d_ws, size_t ws_size,
                              hipStream_t stream) {
    const float* src = (const float*)d_in[0];
    const float* tgt = (const float*)d_in[1];
    float* out = (float*)d_out;

    char* ws = (char*)d_ws;
    float*  scale  = (float*)(ws + 16);                          // 4 B
    float*  sq     = (float*)(ws + 64);                          // 32768 B
    float*  part   = (float*)(ws + 64 + 32768);                  // 256*256*4 B
    double* parts1 = (double*)(ws + 64 + 32768 + 262144);        // 256*8 B
    unsigned char* hi = (unsigned char*)(ws + 297024);           // 2 MB, 16B-aligned
    float*  pb     = (float*)(ws + 2394176);                     // 2080*4 B

    k_conv <<<CONVB, 256, 0, stream>>>(src, tgt, hi, sq, part, parts1, out);
    k_scale<<<1, 256, 0, stream>>>(parts1, part, scale);
    k_pairs<<<NTILE, 256, 0, stream>>>(hi, sq, scale, pb);
    k_fin  <<<1, 256, 0, stream>>>(pb, out);
}

// Round 9
// 96.345 us; speedup vs baseline: 2.6839x; 1.0117x over previous
//
#include <hip/hip_runtime.h>

// MMD loss, N=4096 per side, D=256, fp32.
// R25: persistent pipelined k_pairs (T14 async-stage). R24 measured: packed
//      epilogue -4 us (97.5 total); k_pairs ~29 vs component floors {MFMA
//      8.5, epi ~7, stage ~4}. R22 probes: full 27.6/pass < stage 13.8 +
//      nostage 20.7 but >> max() -> stage/compute only PARTIALLY overlap;
//      ~5 us/dispatch launch ramp on top. Fix (one lever): grid 512 fully
//      co-resident (2 blk/CU), each block walks ~4 contiguous tiles of the
//      I-major triangle. Per tile: hoist all 32 fragment ds_read_b128 to
//      regs -> barrier -> issue NEXT tile's DMA (B-only within an I-run;
//      every I-change lands on a diagonal tile so A-restage needs no B)
//      -> MFMA+epilogue from regs WHILE DMA fills LDS -> vmcnt(0)+barrier.
//      Single 64KB LDS buffer (2 blk/CU kept); staging bytes ~halved by
//      A-reuse; ramp paid once not 2080/512 times. VGPR ~222 (<256 @2w/
//      SIMD), all indices statically unrolled.
//      k_conv/k_scale/k_fin/epilogue math FROZEN from R24.
//      Lessons: NO __threadfence (R8-R10), NO cooperative (R17), unrolled
//      indices only (R8/R9), occupancy/bytes/atomics not the lever (R18-
//      R21), binder located by ablation not theory (R22), packed epilogue
//      kept (R24).

#define NROWS 8192
#define HALF  4096
#define DIM   256
#define CONVB 256
#define NTILE 2080        // 128x128 tiles: 64*65/2, J>=I
#define GRIDP 512         // persistent k_pairs blocks, all co-resident

typedef float f32x4 __attribute__((ext_vector_type(4)));
typedef float f32x2 __attribute__((ext_vector_type(2)));

__device__ __forceinline__ const float* row_ptr(const float* src, const float* tgt, int r) {
    return (r < HALF) ? (src + (size_t)r * DIM) : (tgt + (size_t)(r - HALF) * DIM);
}

__device__ __forceinline__ void gload_lds16(const void* g, void* l) {
    __builtin_amdgcn_global_load_lds(
        (const __attribute__((address_space(1))) unsigned int*)g,
        (__attribute__((address_space(3))) unsigned int*)l, 16, 0, 0);
}

// Stage one 128-row fp8 panel (32 KB) into lds; 32 DMA instrs, wave w takes
// k%4==w. Source row pre-swizzled rg = r ^ ((u&3)<<1); LDS linear.
__device__ __forceinline__ void stage_panel(const ulonglong2* plane, int P,
                                            ulonglong2* lds, int w, int lane) {
    #pragma unroll
    for (int i = 0; i < 8; ++i) {
        int k = w + 4 * i;                  // 0..31, wave-uniform split
        int u = k >> 1;
        int h = k & 1;
        int rg = (h * 64 + lane) ^ ((u & 3) << 1);
        gload_lds16(plane + (size_t)P * 2048 + (size_t)u * 128 + rg,
                    lds + u * 128 + h * 64);
    }
}

// --- Phase 0: fp32 -> fp8 plane (tiled, k-interleaved) + sq/colsum/S1 ---
__global__ __launch_bounds__(256) void k_conv(const float* __restrict__ src,
                                              const float* __restrict__ tgt,
                                              unsigned char* __restrict__ hi,
                                              float* __restrict__ sq,
                                              float* __restrict__ part,
                                              double* __restrict__ parts1,
                                              float* __restrict__ out) {
    __shared__ __align__(16) unsigned char sh8[32 * 256];  // 8 KB, octet-swizzled
    __shared__ float4 cs[4][64];
    __shared__ double s1s[4];

    int w = threadIdx.x >> 6, lane = threadIdx.x & 63;
    int r0 = blockIdx.x * 32;

    float4 v[8];
    #pragma unroll
    for (int i = 0; i < 8; ++i) {
        int row = r0 + w * 8 + i;
        v[i] = ((const float4*)row_ptr(src, tgt, row))[lane];
    }

    float4 csum = {0.f, 0.f, 0.f, 0.f};
    double s1w = 0.0;
    #pragma unroll
    for (int i = 0; i < 8; ++i) {
        int rl  = w * 8 + i;
        float xs[4] = {v[i].x, v[i].y, v[i].z, v[i].w};
        int pk = __builtin_amdgcn_cvt_pk_fp8_f32(xs[0], xs[1], 0, false);
        pk     = __builtin_amdgcn_cvt_pk_fp8_f32(xs[2], xs[3], pk, true);
        int o  = lane >> 1, h = lane & 1;
        *(int*)&sh8[rl * 256 + (((o ^ rl) & 31) << 3) + (h << 2)] = pk;
        csum.x += xs[0]; csum.y += xs[1]; csum.z += xs[2]; csum.w += xs[3];
        float sf = xs[0]*xs[0] + xs[1]*xs[1] + xs[2]*xs[2] + xs[3]*xs[3];
        float q0 = __builtin_amdgcn_cvt_f32_fp8(pk, 0);
        float q1 = __builtin_amdgcn_cvt_f32_fp8(pk, 1);
        float q2 = __builtin_amdgcn_cvt_f32_fp8(pk, 2);
        float q3 = __builtin_amdgcn_cvt_f32_fp8(pk, 3);
        float sQ = q0*q0 + q1*q1 + q2*q2 + q3*q3;
        #pragma unroll
        for (int off = 32; off; off >>= 1) {
            sf += __shfl_xor(sf, off, 64);
            sQ += __shfl_xor(sQ, off, 64);
        }
        if (lane == 0) { sq[r0 + rl] = sQ; s1w += (double)sf; }
    }
    __syncthreads();
    int panel = blockIdx.x >> 2, quarter = blockIdx.x & 3;
    #pragma unroll
    for (int c = threadIdx.x; c < 512; c += 256) {
        int u = c >> 5, rl = c & 31;
        int tt = u >> 2, j = u & 3;
        int o0 = 8 * tt + j;
        int o1 = 8 * tt + 4 + j;
        unsigned long long q0 = *(const unsigned long long*)
            &sh8[rl * 256 + (((o0 ^ rl) & 31) << 3)];
        unsigned long long q1 = *(const unsigned long long*)
            &sh8[rl * 256 + (((o1 ^ rl) & 31) << 3)];
        ulonglong2 q = {q0, q1};
        size_t goff = ((size_t)panel * 2048 + (size_t)u * 128 + quarter * 32 + rl);
        ((ulonglong2*)hi)[goff] = q;
    }
    cs[w][lane] = csum;
    if (lane == 0) s1s[w] = s1w;
    __syncthreads();
    if (w == 0) {
        float4 a = cs[0][lane], b = cs[1][lane], c = cs[2][lane], d = cs[3][lane];
        float4 tot = {a.x + b.x + c.x + d.x, a.y + b.y + c.y + d.y,
                      a.z + b.z + c.z + d.z, a.w + b.w + c.w + d.w};
        *(float4*)&part[(size_t)blockIdx.x * DIM + lane * 4] = tot;
        if (lane == 0) parts1[blockIdx.x] = s1s[0] + s1s[1] + s1s[2] + s1s[3];
    }
    if (blockIdx.x == 0 && threadIdx.x == 0) out[0] = 0.0f;
}

// --- Phase 1: bandwidth -> exp2 scale factor ---
__global__ __launch_bounds__(256) void k_scale(const double* __restrict__ parts1,
                                               const float* __restrict__ part,
                                               float* __restrict__ scale) {
    __shared__ double sh[256];
    int t = threadIdx.x;
    sh[t] = parts1[t];
    __syncthreads();
    for (int off = 128; off; off >>= 1) {
        if (t < off) sh[t] += sh[t + off];
        __syncthreads();
    }
    double S1 = sh[0];
    __syncthreads();
    float c0 = 0.f, c1 = 0.f, c2 = 0.f, c3 = 0.f;
    #pragma unroll 16
    for (int b = 0; b < CONVB; b += 4) {
        c0 += part[(b + 0) * DIM + t];
        c1 += part[(b + 1) * DIM + t];
        c2 += part[(b + 2) * DIM + t];
        c3 += part[(b + 3) * DIM + t];
    }
    double c = (double)((c0 + c1) + (c2 + c3));
    sh[t] = c * c;
    __syncthreads();
    for (int off = 128; off; off >>= 1) {
        if (t < off) sh[t] += sh[t + off];
        __syncthreads();
    }
    if (t == 0) {
        double S2    = sh[0];
        double n     = (double)NROWS;
        double sumL2 = 2.0 * n * S1 - 2.0 * S2;
        double bw    = sumL2 / (n * n - n) / 4.0;
        *scale = (float)(-1.0 / (16.0 * bw * 0.69314718055994530942));
    }
}

// --- Phase 2: persistent pipelined fp8 MFMA pair kernel ---
__global__ __launch_bounds__(256, 2) void k_pairs(const unsigned char* __restrict__ hi,
                                                  const float* __restrict__ sq,
                                                  const float* __restrict__ scale_p,
                                                  float* __restrict__ pb) {
    __shared__ __align__(16) ulonglong2 ldsA[2048];   // 32 KB: panel I
    __shared__ __align__(16) ulonglong2 ldsB[2048];   // 32 KB: panel J
    __shared__ float wsum[4];

    int bid = blockIdx.x;
    int t0 = (bid * NTILE) / GRIDP;
    int t1 = ((bid + 1) * NTILE) / GRIDP;

    // Decode start tile t0 -> (I, J) in I-major triangle order.
    int id = t0, I = 0;
    for (;;) {
        int c = 64 - I;
        if (id < c) break;
        id -= c; ++I;
    }
    int J = I + id;

    int t    = threadIdx.x;
    int lane = t & 63;
    int w    = t >> 6;
    int lr   = lane & 15, lq = lane >> 4;
    int wr   = w >> 1, wc = w & 1;
    int lrx  = lr ^ (lq << 1);

    const ulonglong2* plane = (const ulonglong2*)hi;
    float s = *scale_p;
    f32x2 m2s = {-2.0f * s, -2.0f * s};

    // Prologue: stage first tile's panels.
    stage_panel(plane, I, ldsA, w, lane);
    if (J != I) stage_panel(plane, J, ldsB, w, lane);
    asm volatile("s_waitcnt vmcnt(0)");
    __syncthreads();

    float wtot = 0.0f;
    int curI = I, curJ = J;

    #pragma unroll 1
    for (int tile = t0; tile < t1; ++tile) {
        const ulonglong2* lB  = (curJ == curI) ? ldsA : ldsB;
        const ulonglong2* pAl = ldsA + lq * 128 + wr * 64 + lrx;
        const ulonglong2* pBl = lB   + lq * 128 + wc * 64 + lrx;

        // Hoist ALL 32 fragment reads to registers (frees LDS for prefetch).
        ulonglong2 fA[4][4], fB[4][4];
        #pragma unroll
        for (int tt = 0; tt < 4; ++tt) {
            #pragma unroll
            for (int m = 0; m < 4; ++m) fA[tt][m] = pAl[tt * 512 + m * 16];
            #pragma unroll
            for (int n = 0; n < 4; ++n) fB[tt][n] = pBl[tt * 512 + n * 16];
        }
        __syncthreads();   // all waves' LDS reads retired (lgkmcnt auto)

        // Issue NEXT tile's DMA now; it fills LDS under the MFMA+epilogue.
        int nI = curI, nJ = curJ + 1;
        if (nJ == 64) { nI = curI + 1; nJ = nI; }
        if (tile + 1 < t1) {
            if (nI != curI) stage_panel(plane, nI, ldsA, w, lane);  // diag next: B aliases A
            else            stage_panel(plane, nJ, ldsB, w, lane);  // same-I run: B only
        }

        // MFMA from registers.
        f32x4 acc[4][4];
        #pragma unroll
        for (int m = 0; m < 4; ++m)
            #pragma unroll
            for (int n = 0; n < 4; ++n) acc[m][n] = (f32x4){0.f, 0.f, 0.f, 0.f};
        #pragma unroll
        for (int tt = 0; tt < 4; ++tt) {
            #pragma unroll
            for (int m = 0; m < 4; ++m)
                #pragma unroll
                for (int n = 0; n < 4; ++n)
                    acc[m][n] = __builtin_amdgcn_mfma_f32_16x16x32_fp8_fp8(
                        (long)fA[tt][m].x, (long)fB[tt][n].x, acc[m][n], 0, 0, 0);
            #pragma unroll
            for (int m = 0; m < 4; ++m)
                #pragma unroll
                for (int n = 0; n < 4; ++n)
                    acc[m][n] = __builtin_amdgcn_mfma_f32_16x16x32_fp8_fp8(
                        (long)fA[tt][m].y, (long)fB[tt][n].y, acc[m][n], 0, 0, 0);
        }

        // Packed epilogue (frozen R24 math), per-tile weight/sign folded in.
        float wgt = (curJ == curI) ? 1.0f : 2.0f;
        float sgn = ((curI < 32) == (curJ < 32)) ? 1.0f : -1.0f;
        int ro_eff = curI * 128 + wr * 64;
        int co_eff = curJ * 128 + wc * 64;
        float4 sqa4[4];
        float  sqbv[4];
        #pragma unroll
        for (int m = 0; m < 4; ++m) sqa4[m] = *(const float4*)&sq[ro_eff + m * 16 + lq * 4];
        #pragma unroll
        for (int n = 0; n < 4; ++n) sqbv[n] = s * sq[co_eff + n * 16 + lr];

        f32x2 ssa01[4], ssa23[4];
        #pragma unroll
        for (int m = 0; m < 4; ++m) {
            ssa01[m] = (f32x2){s * sqa4[m].x, s * sqa4[m].y};
            ssa23[m] = (f32x2){s * sqa4[m].z, s * sqa4[m].w};
        }

        f32x2 acc0 = {0.f, 0.f}, acc1 = {0.f, 0.f};
        #pragma unroll
        for (int m = 0; m < 4; ++m) {
            #pragma unroll
            for (int n = 0; n < 4; ++n) {
                f32x2 sbn = {sqbv[n], sqbv[n]};
                f32x2 a01 = {acc[m][n][0], acc[m][n][1]};
                f32x2 a23 = {acc[m][n][2], acc[m][n][3]};
                f32x2 e01 = (ssa01[m] + sbn) + m2s * a01;
                f32x2 e23 = (ssa23[m] + sbn) + m2s * a23;
                f32x2 u01, u23;
                u01.x = __builtin_amdgcn_exp2f(e01.x);
                u01.y = __builtin_amdgcn_exp2f(e01.y);
                u23.x = __builtin_amdgcn_exp2f(e23.x);
                u23.y = __builtin_amdgcn_exp2f(e23.y);
                f32x2 p2a = u01 * u01, p4a = p2a * p2a, p8a = p4a * p4a, p16a = p8a * p8a;
                f32x2 p2b = u23 * u23, p4b = p2b * p2b, p8b = p4b * p4b, p16b = p8b * p8b;
                acc0 += ((u01 + p2a) + (p4a + p8a)) + p16a;
                acc1 += ((u23 + p2b) + (p4b + p8b)) + p16b;
            }
        }
        wtot += ((acc0.x + acc0.y) + (acc1.x + acc1.y)) * sgn * wgt;

        // DMA for next tile must be complete before next iter's LDS reads.
        asm volatile("s_waitcnt vmcnt(0)");
        __syncthreads();
        curI = nI; curJ = nJ;
    }

    #pragma unroll
    for (int off = 32; off; off >>= 1) wtot += __shfl_xor(wtot, off, 64);
    if (lane == 0) wsum[w] = wtot;
    __syncthreads();
    if (t == 0) {
        float tot = wsum[0] + wsum[1] + wsum[2] + wsum[3];
        pb[blockIdx.x] = tot * (1.0f / ((float)HALF * (float)HALF));
    }
}

// --- Phase 3: reduce per-block partials -> out ---
__global__ __launch_bounds__(256) void k_fin(const float* __restrict__ pb,
                                             float* __restrict__ out) {
    __shared__ float sh[4];
    int t = threadIdx.x, lane = t & 63, w = t >> 6;
    float s = 0.f;
    for (int i = t; i < GRIDP; i += 256) s += pb[i];
    #pragma unroll
    for (int off = 32; off; off >>= 1) s += __shfl_xor(s, off, 64);
    if (lane == 0) sh[w] = s;
    __syncthreads();
    if (t == 0) out[0] = sh[0] + sh[1] + sh[2] + sh[3];
}

extern "C" void kernel_launch(void* const* d_in, const int* in_sizes, int n_in,
                              void* d_out, int out_size, void* d_ws, size_t ws_size,
                              hipStream_t stream) {
    const float* src = (const float*)d_in[0];
    const float* tgt = (const float*)d_in[1];
    float* out = (float*)d_out;

    char* ws = (char*)d_ws;
    float*  scale  = (float*)(ws + 16);                          // 4 B
    float*  sq     = (float*)(ws + 64);                          // 32768 B
    float*  part   = (float*)(ws + 64 + 32768);                  // 256*256*4 B
    double* parts1 = (double*)(ws + 64 + 32768 + 262144);        // 256*8 B
    unsigned char* hi = (unsigned char*)(ws + 297024);           // 2 MB, 16B-aligned
    float*  pb     = (float*)(ws + 2394176);                     // 512*4 B

    k_conv <<<CONVB, 256, 0, stream>>>(src, tgt, hi, sq, part, parts1, out);
    k_scale<<<1, 256, 0, stream>>>(parts1, part, scale);
    k_pairs<<<GRIDP, 256, 0, stream>>>(hi, sq, scale, pb);
    k_fin  <<<1, 256, 0, stream>>>(pb, out);
}